// Round 1
// baseline (1256.998 us; speedup 1.0000x reference)
//
#include <hip/hip_runtime.h>
#include <hip/hip_bf16.h>
#include <stdint.h>

// Problem constants
#define ALPHA 0.05f
constexpr int B_   = 8;
constexpr int CIN  = 32;
constexpr int NN   = 1024;
constexpr int CC   = 16;
constexpr int HID_ = 20;
constexpr int COUT = 32;
constexpr int PAIRS = B_ * CC;   // 128

typedef __attribute__((ext_vector_type(8))) short bf8;   // 8 bf16 in 4 VGPRs
typedef __attribute__((ext_vector_type(4))) float f4;

__device__ inline unsigned short f2bf(float x) {
    union { float f; uint32_t u; } v; v.f = x;
    uint32_t u = v.u;
    u += 0x7fffu + ((u >> 16) & 1u);   // round-to-nearest-even
    return (unsigned short)(u >> 16);
}

// ---------------------------------------------------------------------------
// K1: h0[pair][n][l] = sum_i x[b][i][n][c] * W_start[i][l] + b_start[l]
//     pair = b*16 + c.  grid: (64 n-tiles, 8 b), block 256.
// ---------------------------------------------------------------------------
__global__ __launch_bounds__(256) void k_h0(const float* __restrict__ x,
                                            const float* __restrict__ Ws,
                                            const float* __restrict__ bs,
                                            float* __restrict__ h0) {
    int b = blockIdx.y, n0 = blockIdx.x * 16;
    __shared__ float xs[CIN * 16 * CC];   // [i][nl][c], 32 KB
    __shared__ float WsS[CIN * HID_];
    __shared__ float bsS[HID_];
    int t = threadIdx.x;

    // stage x: per i, 256 contiguous floats (16 n x 16 c) = 64 float4
    #pragma unroll
    for (int j = 0; j < 8; j++) {
        int idx = t + j * 256;            // 0..2047
        int i = idx >> 6, f = idx & 63;
        ((float4*)xs)[idx] =
            ((const float4*)(x + ((size_t)(b * CIN + i) * NN + n0) * CC))[f];
    }
    for (int j = t; j < CIN * HID_; j += 256) WsS[j] = Ws[j];
    if (t < HID_) bsS[t] = bs[t];
    __syncthreads();

    int c = t & 15, nl = t >> 4;
    float acc[HID_];
    #pragma unroll
    for (int l = 0; l < HID_; l++) acc[l] = bsS[l];
    for (int i = 0; i < CIN; i++) {
        float xv = xs[i * 256 + nl * 16 + c];
        #pragma unroll
        for (int l = 0; l < HID_; l++) acc[l] += xv * WsS[i * HID_ + l];
    }
    float* dst = h0 + ((size_t)(b * CC + c) * NN + (n0 + nl)) * HID_;
    #pragma unroll
    for (int l = 0; l < HID_; l++) dst[l] = acc[l];
}

// ---------------------------------------------------------------------------
// T: build B^T for the MFMA pass: hbt[pair][l][k] (bf16), rows 0..19 = h^T,
//    row 20 = 1.0 (rowsum trick), rows 21..31 = 0.  grid: (8 k-tiles, 128).
// ---------------------------------------------------------------------------
__global__ __launch_bounds__(256) void k_hT(const float* __restrict__ h,
                                            unsigned short* __restrict__ hbt) {
    int pair = blockIdx.y, k0 = blockIdx.x * 128;
    int t = threadIdx.x;
    for (int idx = t; idx < 32 * 128; idx += 256) {
        int l = idx >> 7, kk = idx & 127;
        float v;
        if (l < HID_)      v = h[((size_t)pair * NN + k0 + kk) * HID_ + l];
        else if (l == HID_) v = 1.0f;
        else                v = 0.0f;
        hbt[((size_t)pair * 32 + l) * NN + k0 + kk] = f2bf(v);
    }
}

// ---------------------------------------------------------------------------
// P: one propagation pass.
//    u[v][0:20] = adj_bf16 @ h_prev ;  u[v][20] = rowsum(adj[v])
//    s = u[20] + 1 ;  h_out = ALPHA*h0 + (1-ALPHA)*(u + h_in[v])/s
//    grid: (8 m-tiles, 128 pairs), block 256 (4 waves), MFMA 16x16x32 bf16.
// ---------------------------------------------------------------------------
constexpr int MT = 128;       // rows per block
constexpr int KC = 128;       // k-chunk
constexpr int ASTR = 136;     // LDS row stride in bf16 (+8 pad, keeps 16B align)

__global__ __launch_bounds__(256) void k_prop(
        const float* __restrict__ adj,          // [128][1024][1024] f32
        const unsigned short* __restrict__ hbt, // [128][32][1024] bf16 (B^T)
        const float* __restrict__ h_in,         // f32, for identity add
        const float* __restrict__ h0,           // f32, for alpha mix
        float* __restrict__ h_out) {
    int pair = blockIdx.y;
    int m0 = blockIdx.x * MT;
    __shared__ unsigned short As[MT * ASTR];    // 34 KB
    __shared__ unsigned short Ht[32 * ASTR];    // 8.5 KB
    int t = threadIdx.x;
    int lane = t & 63, wave = t >> 6;
    int ml = lane & 15, quad = lane >> 4;

    f4 acc[2][2];
    #pragma unroll
    for (int mt = 0; mt < 2; mt++)
        #pragma unroll
        for (int nt = 0; nt < 2; nt++)
            #pragma unroll
            for (int r = 0; r < 4; r++) acc[mt][nt][r] = 0.0f;

    const float* adjp = adj + (size_t)pair * NN * NN + (size_t)m0 * NN;
    const unsigned short* hbp = hbt + (size_t)pair * 32 * NN;

    for (int kc = 0; kc < NN; kc += KC) {
        __syncthreads();
        // stage A tile: 128 rows x 128 cols, f32 -> bf16 (two half-batches)
        #pragma unroll
        for (int half = 0; half < 2; half++) {
            float4 tmp[8];
            #pragma unroll
            for (int j = 0; j < 8; j++) {
                int idx = t + (half * 8 + j) * 256;  // 0..4095
                int r = idx >> 5, c4 = idx & 31;
                tmp[j] = ((const float4*)(adjp + (size_t)r * NN + kc))[c4];
            }
            #pragma unroll
            for (int j = 0; j < 8; j++) {
                int idx = t + (half * 8 + j) * 256;
                int r = idx >> 5, c4 = idx & 31;
                uint2 w;
                w.x = (uint32_t)f2bf(tmp[j].x) | ((uint32_t)f2bf(tmp[j].y) << 16);
                w.y = (uint32_t)f2bf(tmp[j].z) | ((uint32_t)f2bf(tmp[j].w) << 16);
                *(uint2*)&As[r * ASTR + c4 * 4] = w;
            }
        }
        // stage Ht chunk: 32 rows x 128 bf16 (already transposed in global)
        #pragma unroll
        for (int j = 0; j < 2; j++) {
            int idx = t + j * 256;                   // 0..511
            int l = idx >> 4, seg = idx & 15;
            *(uint4*)&Ht[l * ASTR + seg * 8] =
                *(const uint4*)&hbp[(size_t)l * NN + kc + seg * 8];
        }
        __syncthreads();
        // compute: 4 k-steps of 32
        #pragma unroll
        for (int ks = 0; ks < KC; ks += 32) {
            bf8 a[2], b[2];
            #pragma unroll
            for (int mt = 0; mt < 2; mt++)
                a[mt] = *(const bf8*)&As[(wave * 32 + mt * 16 + ml) * ASTR + ks + quad * 8];
            #pragma unroll
            for (int nt = 0; nt < 2; nt++)
                b[nt] = *(const bf8*)&Ht[(nt * 16 + ml) * ASTR + ks + quad * 8];
            #pragma unroll
            for (int mt = 0; mt < 2; mt++)
                #pragma unroll
                for (int nt = 0; nt < 2; nt++)
                    acc[mt][nt] = __builtin_amdgcn_mfma_f32_16x16x32_bf16(
                        a[mt], b[nt], acc[mt][nt], 0, 0, 0);
        }
    }

    // epilogue: C/D layout col = lane&15 (+16*nt), row = quad*4 + reg
    #pragma unroll
    for (int mt = 0; mt < 2; mt++) {
        #pragma unroll
        for (int r = 0; r < 4; r++) {
            int row = m0 + wave * 32 + mt * 16 + quad * 4 + r;
            // s lives in col 20 = (nt=1, ml==4), same quad
            float s = __shfl(acc[mt][1][r], (quad << 4) + 4, 64) + 1.0f;
            float inv_s = (1.0f - ALPHA) / s;
            {
                int col = ml;                        // 0..15 < 20: always valid
                size_t off = ((size_t)pair * NN + row) * HID_ + col;
                h_out[off] = ALPHA * h0[off] + inv_s * (acc[mt][0][r] + h_in[off]);
            }
            if (ml < 4) {
                int col = 16 + ml;                   // 16..19
                size_t off = ((size_t)pair * NN + row) * HID_ + col;
                h_out[off] = ALPHA * h0[off] + inv_s * (acc[mt][1][r] + h_in[off]);
            }
        }
    }
}

// ---------------------------------------------------------------------------
// K3: out[pair][n][o] = sum_k [h0|h1|h2|h3][pair][n][k] * W_end[k][o] + b_end[o]
//     grid: (8 n-tiles of 128, 128 pairs), block 256.
//     Thread tile: 4 n-rows x 4 o-cols; W_end^T staged in LDS (stride 84).
// ---------------------------------------------------------------------------
__global__ __launch_bounds__(256) void k_out(const float* __restrict__ h0,
                                             const float* __restrict__ h1,
                                             const float* __restrict__ h2,
                                             const float* __restrict__ h3,
                                             const float* __restrict__ We,
                                             const float* __restrict__ be,
                                             float* __restrict__ out) {
    int pair = blockIdx.y, n0 = blockIdx.x * 128;
    int t = threadIdx.x;
    __shared__ float WeT[32 * 84];   // WeT[o][k], stride 84 (bank-friendly)
    __shared__ float beS[32];
    for (int idx = t; idx < 80 * 32; idx += 256) {
        int k = idx >> 5, o = idx & 31;
        WeT[o * 84 + k] = We[idx];
    }
    if (t < 32) beS[t] = be[t];
    __syncthreads();

    const float* hs[4] = {h0, h1, h2, h3};
    int og = t & 7, ng = t >> 3;     // o = og + c*8 ; n = n0 + ng + r*32
    float acc[4][4];
    #pragma unroll
    for (int r = 0; r < 4; r++)
        #pragma unroll
        for (int c = 0; c < 4; c++) acc[r][c] = beS[og + c * 8];

    #pragma unroll
    for (int src = 0; src < 4; src++) {
        const float* hp = hs[src] + ((size_t)pair * NN + n0 + ng) * HID_;
        #pragma unroll
        for (int j = 0; j < 5; j++) {
            float4 hv[4];
            #pragma unroll
            for (int r = 0; r < 4; r++)
                hv[r] = *(const float4*)(hp + (size_t)(r * 32) * HID_ + j * 4);
            #pragma unroll
            for (int c = 0; c < 4; c++) {
                float4 wv = *(const float4*)&WeT[(og + c * 8) * 84 + src * 20 + j * 4];
                #pragma unroll
                for (int r = 0; r < 4; r++)
                    acc[r][c] += hv[r].x * wv.x + hv[r].y * wv.y +
                                 hv[r].z * wv.z + hv[r].w * wv.w;
            }
        }
    }
    #pragma unroll
    for (int r = 0; r < 4; r++)
        #pragma unroll
        for (int c = 0; c < 4; c++)
            out[((size_t)pair * NN + n0 + ng + r * 32) * COUT + og + c * 8] = acc[r][c];
}

// ---------------------------------------------------------------------------
extern "C" void kernel_launch(void* const* d_in, const int* in_sizes, int n_in,
                              void* d_out, int out_size, void* d_ws, size_t ws_size,
                              hipStream_t stream) {
    const float* x   = (const float*)d_in[0];
    const float* adj = (const float*)d_in[1];
    const float* Ws  = (const float*)d_in[2];
    const float* bs  = (const float*)d_in[3];
    const float* We  = (const float*)d_in[4];
    const float* be  = (const float*)d_in[5];
    float* out = (float*)d_out;

    const size_t HSZ = (size_t)PAIRS * NN * HID_;   // 2,621,440 floats
    float* h0 = (float*)d_ws;
    float* h1 = h0 + HSZ;
    float* h2 = h1 + HSZ;
    float* h3 = h2 + HSZ;
    unsigned short* hbt = (unsigned short*)(h3 + HSZ);  // [128][32][1024] bf16

    k_h0 <<<dim3(64, 8),  256, 0, stream>>>(x, Ws, bs, h0);

    k_hT  <<<dim3(8, PAIRS), 256, 0, stream>>>(h0, hbt);
    k_prop<<<dim3(8, PAIRS), 256, 0, stream>>>(adj, hbt, h0, h0, h1);

    k_hT  <<<dim3(8, PAIRS), 256, 0, stream>>>(h1, hbt);
    k_prop<<<dim3(8, PAIRS), 256, 0, stream>>>(adj, hbt, h1, h0, h2);

    k_hT  <<<dim3(8, PAIRS), 256, 0, stream>>>(h2, hbt);
    k_prop<<<dim3(8, PAIRS), 256, 0, stream>>>(adj, hbt, h2, h0, h3);

    k_out <<<dim3(8, PAIRS), 256, 0, stream>>>(h0, h1, h2, h3, We, be, out);
}

// Round 2
// 1052.055 us; speedup vs baseline: 1.1948x; 1.1948x over previous
//
#include <hip/hip_runtime.h>
#include <hip/hip_bf16.h>
#include <stdint.h>

#define ALPHA 0.05f
constexpr int B_   = 8;
constexpr int CIN  = 32;
constexpr int NN   = 1024;
constexpr int CC   = 16;
constexpr int HID_ = 20;
constexpr int COUT = 32;
constexpr int PAIRS = B_ * CC;   // 128

typedef __attribute__((ext_vector_type(8))) short bf8;   // 8 bf16 in 4 VGPRs
typedef __attribute__((ext_vector_type(4))) float f4;

__device__ inline unsigned short f2bf(float x) {
    union { float f; uint32_t u; } v; v.f = x;
    uint32_t u = v.u;
    u += 0x7fffu + ((u >> 16) & 1u);   // round-to-nearest-even
    return (unsigned short)(u >> 16);
}

__device__ inline bf8 pack8(float4 lo, float4 hi) {
    bf8 r;
    r[0] = (short)f2bf(lo.x); r[1] = (short)f2bf(lo.y);
    r[2] = (short)f2bf(lo.z); r[3] = (short)f2bf(lo.w);
    r[4] = (short)f2bf(hi.x); r[5] = (short)f2bf(hi.y);
    r[6] = (short)f2bf(hi.z); r[7] = (short)f2bf(hi.w);
    return r;
}

// ---------------------------------------------------------------------------
// K1: h0[pair][n][l] = sum_i x[b][i][n][c] * W_start[i][l] + b_start[l]
// ---------------------------------------------------------------------------
__global__ __launch_bounds__(256) void k_h0(const float* __restrict__ x,
                                            const float* __restrict__ Ws,
                                            const float* __restrict__ bs,
                                            float* __restrict__ h0) {
    int b = blockIdx.y, n0 = blockIdx.x * 16;
    __shared__ float xs[CIN * 16 * CC];   // [i][nl][c], 32 KB
    __shared__ float WsS[CIN * HID_];
    __shared__ float bsS[HID_];
    int t = threadIdx.x;

    #pragma unroll
    for (int j = 0; j < 8; j++) {
        int idx = t + j * 256;            // 0..2047
        int i = idx >> 6, f = idx & 63;
        ((float4*)xs)[idx] =
            ((const float4*)(x + ((size_t)(b * CIN + i) * NN + n0) * CC))[f];
    }
    for (int j = t; j < CIN * HID_; j += 256) WsS[j] = Ws[j];
    if (t < HID_) bsS[t] = bs[t];
    __syncthreads();

    int c = t & 15, nl = t >> 4;
    float acc[HID_];
    #pragma unroll
    for (int l = 0; l < HID_; l++) acc[l] = bsS[l];
    for (int i = 0; i < CIN; i++) {
        float xv = xs[i * 256 + nl * 16 + c];
        #pragma unroll
        for (int l = 0; l < HID_; l++) acc[l] += xv * WsS[i * HID_ + l];
    }
    float* dst = h0 + ((size_t)(b * CC + c) * NN + (n0 + nl)) * HID_;
    #pragma unroll
    for (int l = 0; l < HID_; l++) dst[l] = acc[l];
}

// ---------------------------------------------------------------------------
// P: one propagation pass — barrier-free K-loop.
//    B^T (32 x 1024 bf16: rows 0..19 = h^T, row 20 = ones, 21..31 = 0) staged
//    once in LDS. Each wave streams 32 adj rows; A-frags loaded straight from
//    global (f32 -> bf16 in regs), register ping-pong prefetch, 4 MFMA/step.
//    s = rowsum (col 20) + 1 ; h_out = ALPHA*h0 + (1-ALPHA)*(u + h_in)/s
//    grid: (4 m-tiles of 256, 128 pairs), block 512 (8 waves).
// ---------------------------------------------------------------------------
constexpr int BSTR = 1032;   // LDS row stride in bf16 (+8 pad; 516 words % 32 = 4)

__global__ __launch_bounds__(512, 4) void k_prop(
        const float* __restrict__ adj,    // [128][1024][1024] f32
        const float* __restrict__ h_in,   // f32: B source AND identity add
        const float* __restrict__ h0,     // f32: alpha mix
        float* __restrict__ h_out) {
    int pair = blockIdx.y;
    int m0 = blockIdx.x * 256;
    __shared__ unsigned short Ht[32 * BSTR];   // 66 KB
    int t = threadIdx.x;
    int lane = t & 63, wave = t >> 6;
    int ml = lane & 15, quad = lane >> 4;

    // ---- stage B^T (once) ----
    const float* hp = h_in + (size_t)pair * NN * HID_;
    for (int k = t; k < NN; k += 512) {
        float4 v0 = *(const float4*)(hp + (size_t)k * HID_ + 0);
        float4 v1 = *(const float4*)(hp + (size_t)k * HID_ + 4);
        float4 v2 = *(const float4*)(hp + (size_t)k * HID_ + 8);
        float4 v3 = *(const float4*)(hp + (size_t)k * HID_ + 12);
        float4 v4 = *(const float4*)(hp + (size_t)k * HID_ + 16);
        float vv[20] = {v0.x, v0.y, v0.z, v0.w, v1.x, v1.y, v1.z, v1.w,
                        v2.x, v2.y, v2.z, v2.w, v3.x, v3.y, v3.z, v3.w,
                        v4.x, v4.y, v4.z, v4.w};
        #pragma unroll
        for (int l = 0; l < HID_; l++) Ht[l * BSTR + k] = f2bf(vv[l]);
    }
    {   // rows 20 (ones) and 21..31 (zeros), vectorized
        uint4 ones; ones.x = ones.y = ones.z = ones.w = 0x3F803F80u;
        uint4 zero; zero.x = zero.y = zero.z = zero.w = 0u;
        for (int idx = t; idx < 12 * (NN / 8); idx += 512) {
            int row = 20 + (idx >> 7), seg = idx & 127;
            *(uint4*)&Ht[row * BSTR + seg * 8] = (row == 20) ? ones : zero;
        }
    }
    __syncthreads();

    // ---- K-loop (no barriers) ----
    f4 acc[2][2];
    #pragma unroll
    for (int mt = 0; mt < 2; mt++)
        #pragma unroll
        for (int nt = 0; nt < 2; nt++)
            #pragma unroll
            for (int r = 0; r < 4; r++) acc[mt][nt][r] = 0.0f;

    const float* a0p = adj + ((size_t)pair * NN + (m0 + wave * 32 + ml)) * NN + quad * 8;
    const float* a1p = a0p + (size_t)16 * NN;
    const int b0off = ml * BSTR + quad * 8;
    const int b1off = b0off + 16 * BSTR;

    float4 c00 = *(const float4*)(a0p + 0);
    float4 c01 = *(const float4*)(a0p + 4);
    float4 c10 = *(const float4*)(a1p + 0);
    float4 c11 = *(const float4*)(a1p + 4);

    #pragma unroll 1
    for (int ks = 0; ks < NN; ks += 64) {
        // -- step A: consume ks (in c*), prefetch ks+32 (into n*)
        float4 n00 = *(const float4*)(a0p + ks + 32);
        float4 n01 = *(const float4*)(a0p + ks + 36);
        float4 n10 = *(const float4*)(a1p + ks + 32);
        float4 n11 = *(const float4*)(a1p + ks + 36);
        {
            bf8 b0 = *(const bf8*)&Ht[b0off + ks];
            bf8 b1 = *(const bf8*)&Ht[b1off + ks];
            bf8 a0 = pack8(c00, c01);
            bf8 a1 = pack8(c10, c11);
            acc[0][0] = __builtin_amdgcn_mfma_f32_16x16x32_bf16(a0, b0, acc[0][0], 0, 0, 0);
            acc[0][1] = __builtin_amdgcn_mfma_f32_16x16x32_bf16(a0, b1, acc[0][1], 0, 0, 0);
            acc[1][0] = __builtin_amdgcn_mfma_f32_16x16x32_bf16(a1, b0, acc[1][0], 0, 0, 0);
            acc[1][1] = __builtin_amdgcn_mfma_f32_16x16x32_bf16(a1, b1, acc[1][1], 0, 0, 0);
        }
        // -- step B: consume ks+32 (in n*), prefetch ks+64 (into c*, wrap-guarded)
        int k2 = (ks + 64 < NN) ? (ks + 64) : 0;
        c00 = *(const float4*)(a0p + k2);
        c01 = *(const float4*)(a0p + k2 + 4);
        c10 = *(const float4*)(a1p + k2);
        c11 = *(const float4*)(a1p + k2 + 4);
        {
            bf8 b0 = *(const bf8*)&Ht[b0off + ks + 32];
            bf8 b1 = *(const bf8*)&Ht[b1off + ks + 32];
            bf8 a0 = pack8(n00, n01);
            bf8 a1 = pack8(n10, n11);
            acc[0][0] = __builtin_amdgcn_mfma_f32_16x16x32_bf16(a0, b0, acc[0][0], 0, 0, 0);
            acc[0][1] = __builtin_amdgcn_mfma_f32_16x16x32_bf16(a0, b1, acc[0][1], 0, 0, 0);
            acc[1][0] = __builtin_amdgcn_mfma_f32_16x16x32_bf16(a1, b0, acc[1][0], 0, 0, 0);
            acc[1][1] = __builtin_amdgcn_mfma_f32_16x16x32_bf16(a1, b1, acc[1][1], 0, 0, 0);
        }
    }

    // ---- epilogue: C/D layout col = lane&15 (+16*nt), row = quad*4 + reg ----
    #pragma unroll
    for (int mt = 0; mt < 2; mt++) {
        #pragma unroll
        for (int r = 0; r < 4; r++) {
            int row = m0 + wave * 32 + mt * 16 + quad * 4 + r;
            float s = __shfl(acc[mt][1][r], (quad << 4) + 4, 64) + 1.0f;
            float inv_s = (1.0f - ALPHA) / s;
            {
                size_t off = ((size_t)pair * NN + row) * HID_ + ml;
                h_out[off] = ALPHA * h0[off] + inv_s * (acc[mt][0][r] + h_in[off]);
            }
            if (ml < 4) {
                size_t off = ((size_t)pair * NN + row) * HID_ + 16 + ml;
                h_out[off] = ALPHA * h0[off] + inv_s * (acc[mt][1][r] + h_in[off]);
            }
        }
    }
}

// ---------------------------------------------------------------------------
// K3: out[pair][n][o] = sum_k [h0|h1|h2|h3][pair][n][k] * W_end[k][o] + b_end[o]
// ---------------------------------------------------------------------------
__global__ __launch_bounds__(256) void k_out(const float* __restrict__ h0,
                                             const float* __restrict__ h1,
                                             const float* __restrict__ h2,
                                             const float* __restrict__ h3,
                                             const float* __restrict__ We,
                                             const float* __restrict__ be,
                                             float* __restrict__ out) {
    int pair = blockIdx.y, n0 = blockIdx.x * 128;
    int t = threadIdx.x;
    __shared__ float WeT[32 * 84];   // WeT[o][k]
    __shared__ float beS[32];
    for (int idx = t; idx < 80 * 32; idx += 256) {
        int k = idx >> 5, o = idx & 31;
        WeT[o * 84 + k] = We[idx];
    }
    if (t < 32) beS[t] = be[t];
    __syncthreads();

    const float* hs[4] = {h0, h1, h2, h3};
    int og = t & 7, ng = t >> 3;
    float acc[4][4];
    #pragma unroll
    for (int r = 0; r < 4; r++)
        #pragma unroll
        for (int c = 0; c < 4; c++) acc[r][c] = beS[og + c * 8];

    #pragma unroll
    for (int src = 0; src < 4; src++) {
        const float* hp = hs[src] + ((size_t)pair * NN + n0 + ng) * HID_;
        #pragma unroll
        for (int j = 0; j < 5; j++) {
            float4 hv[4];
            #pragma unroll
            for (int r = 0; r < 4; r++)
                hv[r] = *(const float4*)(hp + (size_t)(r * 32) * HID_ + j * 4);
            #pragma unroll
            for (int c = 0; c < 4; c++) {
                float4 wv = *(const float4*)&WeT[(og + c * 8) * 84 + src * 20 + j * 4];
                #pragma unroll
                for (int r = 0; r < 4; r++)
                    acc[r][c] += hv[r].x * wv.x + hv[r].y * wv.y +
                                 hv[r].z * wv.z + hv[r].w * wv.w;
            }
        }
    }
    #pragma unroll
    for (int r = 0; r < 4; r++)
        #pragma unroll
        for (int c = 0; c < 4; c++)
            out[((size_t)pair * NN + n0 + ng + r * 32) * COUT + og + c * 8] = acc[r][c];
}

// ---------------------------------------------------------------------------
extern "C" void kernel_launch(void* const* d_in, const int* in_sizes, int n_in,
                              void* d_out, int out_size, void* d_ws, size_t ws_size,
                              hipStream_t stream) {
    const float* x   = (const float*)d_in[0];
    const float* adj = (const float*)d_in[1];
    const float* Ws  = (const float*)d_in[2];
    const float* bs  = (const float*)d_in[3];
    const float* We  = (const float*)d_in[4];
    const float* be  = (const float*)d_in[5];
    float* out = (float*)d_out;

    const size_t HSZ = (size_t)PAIRS * NN * HID_;
    float* h0 = (float*)d_ws;
    float* h1 = h0 + HSZ;
    float* h2 = h1 + HSZ;
    float* h3 = h2 + HSZ;

    k_h0  <<<dim3(64, 8),    256, 0, stream>>>(x, Ws, bs, h0);
    k_prop<<<dim3(4, PAIRS), 512, 0, stream>>>(adj, h0, h0, h1);
    k_prop<<<dim3(4, PAIRS), 512, 0, stream>>>(adj, h1, h0, h2);
    k_prop<<<dim3(4, PAIRS), 512, 0, stream>>>(adj, h2, h0, h3);
    k_out <<<dim3(8, PAIRS), 256, 0, stream>>>(h0, h1, h2, h3, We, be, out);
}